// Round 2
// baseline (129.454 us; speedup 1.0000x reference)
//
#include <hip/hip_runtime.h>
#include <hip/hip_bf16.h>

// MILAttentionPool: B=32, L=2048, D=512, H=256, K=4
// out[b, k*512+d] = sum_l softmax_l(logit[b,l,k]) * x[b*L+l, d]
// logit = (tanh(x@W1+b1)*sigmoid(x@W3+b3)) @ W2   (+b2 cancels in softmax)

typedef short  bf16x8 __attribute__((ext_vector_type(8)));
typedef float  f32x4  __attribute__((ext_vector_type(4)));

#define N_TOT   65536
#define D_IN    512
#define H_DIM   256
#define B_BAGS  32
#define L_BAG   2048

#define XSTR    72     // LDS x-tile row stride in shorts (144B -> 2-way-free banks)

__device__ __forceinline__ short f2bf(float f) {
  union { __hip_bfloat16 h; short s; } u;
  u.h = __float2bfloat16(f);
  return u.s;
}

// ---------------- k0: W1/W3 -> bf16, blocked-transposed [K/32][256][32] ----------------
__global__ __launch_bounds__(256) void k_prep_w(const float* __restrict__ W1,
                                                const float* __restrict__ W3,
                                                short* __restrict__ w1b,
                                                short* __restrict__ w3b) {
  int idx = blockIdx.x * 256 + threadIdx.x;      // 0 .. 262143
  int which = idx >> 17;
  int rem = idx & 131071;
  int k = rem >> 8;          // 0..511
  int n = rem & 255;         // 0..255
  const float* src = which ? W3 : W1;
  short* dst = which ? w3b : w1b;
  dst[(k >> 5) * 8192 + n * 32 + (k & 31)] = f2bf(src[k * H_DIM + n]);
}

// ---------------- k1: fused gate GEMMs (bf16 MFMA) + logits = gate@W2 ----------------
// 512 thr = 8 waves in 4(row)x2(col) grid; wave tile 32x128; block tile 128x256.
// BK=64 (two 16x16x32 K-steps per LDS tile), x double-buffered in LDS,
// weights read per-lane straight from L2 (512KB resident), 1-step reg prefetch.
__global__ __launch_bounds__(512, 2) void k_gate_logits(
    const float* __restrict__ x,
    const short* __restrict__ w1b, const short* __restrict__ w3b,
    const float* __restrict__ b1, const float* __restrict__ b3,
    const float* __restrict__ W2,
    float* __restrict__ logits)
{
  __shared__ __align__(16) short xs0[128 * XSTR];   // 18432 B
  __shared__ __align__(16) short xs1[128 * XSTR];   // 18432 B
  __shared__ __align__(16) float w2s[H_DIM * 4];    //  4096 B
  __shared__ float lpart[2][128][4];                //  4096 B   (total ~45 KB)

  const int tid  = threadIdx.x;
  const int lane = tid & 63;
  const int wid  = tid >> 6;
  const int wrow = wid >> 1;       // 0..3  (32-row band)
  const int wcol = wid & 1;        // 0..1  (128-col band)
  const long row0 = (long)blockIdx.x * 128;

  if (tid < 256) ((f32x4*)w2s)[tid] = ((const f32x4*)W2)[tid];

  f32x4 acc1[2][8], acc3[2][8];
  #pragma unroll
  for (int m = 0; m < 2; ++m)
    #pragma unroll
    for (int n = 0; n < 8; ++n) {
      acc1[m][n] = (f32x4){0.f, 0.f, 0.f, 0.f};
      acc3[m][n] = (f32x4){0.f, 0.f, 0.f, 0.f};
    }

  // x staging: thread loads row xr, 16 cols starting at jc (within 64-col tile)
  const int xr = tid >> 2;            // 0..127
  const int jc = (tid & 3) * 16;      // 0,16,32,48
  const float* xrow = x + (row0 + xr) * D_IN;

  // B fragments: per-lane direct-from-L2
  const int lcol   = wcol * 128 + (lane & 15);
  const int khalf8 = (lane >> 4) * 8;
  const short* w1p = w1b + lcol * 32 + khalf8;
  const short* w3p = w3b + lcol * 32 + khalf8;

  bf16x8 bw1[8], bw3[8];
  float4 xf0, xf1, xf2, xf3;

#define LOADX(kt)                                                   \
  { const float4* p = (const float4*)(xrow + (kt) * 64 + jc);       \
    xf0 = p[0]; xf1 = p[1]; xf2 = p[2]; xf3 = p[3]; }

#define WRITEX(dst)                                                 \
  { bf16x8 v0, v1;                                                  \
    v0[0]=f2bf(xf0.x); v0[1]=f2bf(xf0.y); v0[2]=f2bf(xf0.z); v0[3]=f2bf(xf0.w); \
    v0[4]=f2bf(xf1.x); v0[5]=f2bf(xf1.y); v0[6]=f2bf(xf1.z); v0[7]=f2bf(xf1.w); \
    v1[0]=f2bf(xf2.x); v1[1]=f2bf(xf2.y); v1[2]=f2bf(xf2.z); v1[3]=f2bf(xf2.w); \
    v1[4]=f2bf(xf3.x); v1[5]=f2bf(xf3.y); v1[6]=f2bf(xf3.z); v1[7]=f2bf(xf3.w); \
    *(bf16x8*)&(dst)[xr * XSTR + jc]     = v0;                      \
    *(bf16x8*)&(dst)[xr * XSTR + jc + 8] = v1; }

#define LOADB(s)                                                    \
  { const short* p1 = w1p + (s) * 8192;                             \
    const short* p3 = w3p + (s) * 8192;                             \
    _Pragma("unroll")                                               \
    for (int n = 0; n < 8; ++n) {                                   \
      bw1[n] = *(const bf16x8*)(p1 + n * 512);                      \
      bw3[n] = *(const bf16x8*)(p3 + n * 512);                      \
    } }

  // prologue: stage tile 0, prefetch B(0)
  LOADX(0);
  LOADB(0);
  WRITEX(xs0);
  __syncthreads();

  short* cur = xs0;
  short* nxt = xs1;
  const int rb = wrow * 32 + (lane & 15);

  for (int kt = 0; kt < 8; ++kt) {
    if (kt < 7) LOADX(kt + 1);          // issue next x tile early (HBM in flight)
    #pragma unroll
    for (int half = 0; half < 2; ++half) {
      bf16x8 af0 = *(const bf16x8*)&cur[(rb     ) * XSTR + half * 32 + khalf8];
      bf16x8 af1 = *(const bf16x8*)&cur[(rb + 16) * XSTR + half * 32 + khalf8];
      #pragma unroll
      for (int n = 0; n < 8; ++n) {
        acc1[0][n] = __builtin_amdgcn_mfma_f32_16x16x32_bf16(af0, bw1[n], acc1[0][n], 0, 0, 0);
        acc3[0][n] = __builtin_amdgcn_mfma_f32_16x16x32_bf16(af0, bw3[n], acc3[0][n], 0, 0, 0);
        acc1[1][n] = __builtin_amdgcn_mfma_f32_16x16x32_bf16(af1, bw1[n], acc1[1][n], 0, 0, 0);
        acc3[1][n] = __builtin_amdgcn_mfma_f32_16x16x32_bf16(af1, bw3[n], acc3[1][n], 0, 0, 0);
      }
      if (kt * 2 + half + 1 < 16) LOADB(kt * 2 + half + 1);   // reg prefetch next K-step
    }
    if (kt < 7) WRITEX(nxt);
    __syncthreads();
    short* t = cur; cur = nxt; nxt = t;
  }

  // epilogue: gate = tanh(h1+b1)*sigmoid(h3+b3); partial logits = gate @ W2
  float b1v[8], b3v[8];
  f32x4 wv[8];
  #pragma unroll
  for (int n = 0; n < 8; ++n) {
    int c = wcol * 128 + n * 16 + (lane & 15);
    b1v[n] = b1[c];
    b3v[n] = b3[c];
    wv[n] = *(const f32x4*)&w2s[c * 4];
  }
  float pl[2][4][4];
  #pragma unroll
  for (int m = 0; m < 2; ++m)
    #pragma unroll
    for (int j = 0; j < 4; ++j)
      #pragma unroll
      for (int kk = 0; kk < 4; ++kk) pl[m][j][kk] = 0.f;

  #pragma unroll
  for (int m = 0; m < 2; ++m)
    #pragma unroll
    for (int n = 0; n < 8; ++n)
      #pragma unroll
      for (int j = 0; j < 4; ++j) {
        float h1 = acc1[m][n][j] + b1v[n];
        float h3 = acc3[m][n][j] + b3v[n];
        float th = 1.f - __fdividef(2.f, __expf(2.f * h1) + 1.f);
        float sg = __fdividef(1.f, 1.f + __expf(-h3));
        float g = th * sg;
        pl[m][j][0] += g * wv[n][0];
        pl[m][j][1] += g * wv[n][1];
        pl[m][j][2] += g * wv[n][2];
        pl[m][j][3] += g * wv[n][3];
      }

  #pragma unroll
  for (int off = 1; off < 16; off <<= 1)
    #pragma unroll
    for (int m = 0; m < 2; ++m)
      #pragma unroll
      for (int j = 0; j < 4; ++j)
        #pragma unroll
        for (int kk = 0; kk < 4; ++kk)
          pl[m][j][kk] += __shfl_xor(pl[m][j][kk], off);

  if ((lane & 15) == 0) {
    int lg = lane >> 4;
    #pragma unroll
    for (int m = 0; m < 2; ++m)
      #pragma unroll
      for (int j = 0; j < 4; ++j)
        #pragma unroll
        for (int kk = 0; kk < 4; ++kk)
          lpart[wcol][wrow * 32 + m * 16 + lg * 4 + j][kk] = pl[m][j][kk];
  }
  __syncthreads();

  {
    int r = tid >> 2, kk = tid & 3;   // 512 threads = 128 rows x 4
    logits[(row0 + r) * 4 + kk] = lpart[0][r][kk] + lpart[1][r][kk];
  }
}

// ---------------- k2: per-(bag, head) softmax max & sum ----------------
__global__ __launch_bounds__(256) void k_softmax_stats(const float* __restrict__ logits,
                                                       float* __restrict__ mx,
                                                       float* __restrict__ sm) {
  const int b = blockIdx.x, tid = threadIdx.x;
  const int lane = tid & 63, wid = tid >> 6;
  const float4* L = (const float4*)logits + (long)b * L_BAG;

  float m0 = -3e38f, m1 = m0, m2 = m0, m3 = m0;
  #pragma unroll
  for (int i = 0; i < 8; ++i) {
    float4 v = L[i * 256 + tid];
    m0 = fmaxf(m0, v.x); m1 = fmaxf(m1, v.y); m2 = fmaxf(m2, v.z); m3 = fmaxf(m3, v.w);
  }
  #pragma unroll
  for (int o = 1; o < 64; o <<= 1) {
    m0 = fmaxf(m0, __shfl_xor(m0, o)); m1 = fmaxf(m1, __shfl_xor(m1, o));
    m2 = fmaxf(m2, __shfl_xor(m2, o)); m3 = fmaxf(m3, __shfl_xor(m3, o));
  }
  __shared__ float wr[4][4];
  __shared__ float bm[4];
  if (lane == 0) { wr[wid][0] = m0; wr[wid][1] = m1; wr[wid][2] = m2; wr[wid][3] = m3; }
  __syncthreads();
  if (tid < 4) bm[tid] = fmaxf(fmaxf(wr[0][tid], wr[1][tid]), fmaxf(wr[2][tid], wr[3][tid]));
  __syncthreads();
  m0 = bm[0]; m1 = bm[1]; m2 = bm[2]; m3 = bm[3];

  float s0 = 0.f, s1 = 0.f, s2 = 0.f, s3 = 0.f;
  #pragma unroll
  for (int i = 0; i < 8; ++i) {
    float4 v = L[i * 256 + tid];
    s0 += __expf(v.x - m0); s1 += __expf(v.y - m1);
    s2 += __expf(v.z - m2); s3 += __expf(v.w - m3);
  }
  #pragma unroll
  for (int o = 1; o < 64; o <<= 1) {
    s0 += __shfl_xor(s0, o); s1 += __shfl_xor(s1, o);
    s2 += __shfl_xor(s2, o); s3 += __shfl_xor(s3, o);
  }
  __syncthreads();
  if (lane == 0) { wr[wid][0] = s0; wr[wid][1] = s1; wr[wid][2] = s2; wr[wid][3] = s3; }
  __syncthreads();
  if (tid < 4) {
    mx[b * 4 + tid] = bm[tid];
    sm[b * 4 + tid] = wr[0][tid] + wr[1][tid] + wr[2][tid] + wr[3][tid];
  }
}

// ---------------- k3: partial weighted sums over 128-row chunks ----------------
__global__ __launch_bounds__(128) void k_weighted_partial(const float* __restrict__ x,
                                                          const float* __restrict__ logits,
                                                          const float* __restrict__ mx,
                                                          float* __restrict__ part) {
  const int chunk = blockIdx.x;   // 0..15
  const int b = blockIdx.y;       // 0..31
  const int tid = threadIdx.x;    // 0..127
  const long l0 = (long)b * L_BAG + chunk * 128;

  __shared__ float ep[128][4];
  {
    float4 lg = ((const float4*)logits)[l0 + tid];
    ep[tid][0] = __expf(lg.x - mx[b * 4 + 0]);
    ep[tid][1] = __expf(lg.y - mx[b * 4 + 1]);
    ep[tid][2] = __expf(lg.z - mx[b * 4 + 2]);
    ep[tid][3] = __expf(lg.w - mx[b * 4 + 3]);
  }
  __syncthreads();

  float4 a0 = {0,0,0,0}, a1 = {0,0,0,0}, a2 = {0,0,0,0}, a3 = {0,0,0,0};
  const float4* xp = (const float4*)(x + l0 * D_IN) + tid;
  #pragma unroll 4
  for (int l = 0; l < 128; ++l) {
    float4 xv = xp[l * 128];
    float e0 = ep[l][0], e1 = ep[l][1], e2 = ep[l][2], e3 = ep[l][3];
    a0.x += e0 * xv.x; a0.y += e0 * xv.y; a0.z += e0 * xv.z; a0.w += e0 * xv.w;
    a1.x += e1 * xv.x; a1.y += e1 * xv.y; a1.z += e1 * xv.z; a1.w += e1 * xv.w;
    a2.x += e2 * xv.x; a2.y += e2 * xv.y; a2.z += e2 * xv.z; a2.w += e2 * xv.w;
    a3.x += e3 * xv.x; a3.y += e3 * xv.y; a3.z += e3 * xv.z; a3.w += e3 * xv.w;
  }
  long base = ((long)chunk * 32 + b) * 2048 + tid * 4;
  *(float4*)&part[base +    0] = a0;
  *(float4*)&part[base +  512] = a1;
  *(float4*)&part[base + 1024] = a2;
  *(float4*)&part[base + 1536] = a3;
}

// ---------------- k4: reduce chunks, divide by softmax sum ----------------
__global__ __launch_bounds__(256) void k_finalize(const float* __restrict__ part,
                                                  const float* __restrict__ sm,
                                                  float* __restrict__ out) {
  int idx = blockIdx.x * 256 + threadIdx.x;  // 0..65535 = b*2048 + k*512 + d
  int b = idx >> 11, k = (idx >> 9) & 3;
  float s = 0.f;
  #pragma unroll
  for (int c = 0; c < 16; ++c) s += part[c * 65536 + idx];
  out[idx] = s / sm[b * 4 + k];
}

extern "C" void kernel_launch(void* const* d_in, const int* in_sizes, int n_in,
                              void* d_out, int out_size, void* d_ws, size_t ws_size,
                              hipStream_t stream) {
  const float* x  = (const float*)d_in[0];
  const float* W1 = (const float*)d_in[1];
  const float* b1 = (const float*)d_in[2];
  const float* W3 = (const float*)d_in[3];
  const float* b3 = (const float*)d_in[4];
  const float* W2 = (const float*)d_in[5];
  // d_in[6] = b2: constant over softmax axis -> cancels; d_in[7] = bag_lengths: shapes only
  float* out = (float*)d_out;

  char* ws = (char*)d_ws;                       // ~5.6 MB used
  short* w1b    = (short*)(ws + 0);             // 256 KB
  short* w3b    = (short*)(ws + 262144);        // 256 KB
  float* logits = (float*)(ws + 524288);        // 1 MB
  float* mx     = (float*)(ws + 1572864);       // 512 B
  float* sm     = (float*)(ws + 1573376);       // 512 B
  float* part   = (float*)(ws + 1573888);       // 4 MB

  hipLaunchKernelGGL(k_prep_w,          dim3(1024),    dim3(256), 0, stream, W1, W3, w1b, w3b);
  hipLaunchKernelGGL(k_gate_logits,     dim3(512),     dim3(512), 0, stream, x, w1b, w3b, b1, b3, W2, logits);
  hipLaunchKernelGGL(k_softmax_stats,   dim3(32),      dim3(256), 0, stream, logits, mx, sm);
  hipLaunchKernelGGL(k_weighted_partial,dim3(16, 32),  dim3(128), 0, stream, x, logits, mx, part);
  hipLaunchKernelGGL(k_finalize,        dim3(256),     dim3(256), 0, stream, part, sm, out);
}

// Round 3
// 112.269 us; speedup vs baseline: 1.1531x; 1.1531x over previous
//
#include <hip/hip_runtime.h>
#include <hip/hip_bf16.h>

// MILAttentionPool: B=32, L=2048, D=512, H=256, K=4
// out[b, k*512+d] = sum_l softmax_l(logit[b,l,k]) * x[b*L+l, d]
// logit = (tanh(x@W1+b1)*sigmoid(x@W3+b3)) @ W2   (+b2 cancels in softmax)
//
// k1 = single concat GEMM [65536 x 512] = x @ [W1|W3] (16-col interleave so
// h1/h3 pairs are lane-local), bf16 MFMA, fused gate+W2 epilogue -> logits.

typedef short  bf16x8 __attribute__((ext_vector_type(8)));
typedef float  f32x4  __attribute__((ext_vector_type(4)));

#define D_IN    512
#define H_DIM   256
#define L_BAG   2048

__device__ __forceinline__ short f2bf(float f) {
  union { __hip_bfloat16 h; short s; } u;
  u.h = __float2bfloat16(f);
  return u.s;
}

// ---------------- k0: build concat-interleaved, chunk-major bf16 weights ----------------
// wc tile kt (0..15, 32 k each): short idx = kt*16384 + (c*512 + n_c)*8 + rem
//   kk = kt*32 + c*8 + rem (c=0..3), n_c = concat col: group g=n_c>>5, j=n_c&31,
//   j<16 -> W1[:, g*16+j], else W3[:, g*16+j-16].
__global__ __launch_bounds__(256) void k_prep_w(const float* __restrict__ W1,
                                                const float* __restrict__ W3,
                                                short* __restrict__ wc) {
  int t = blockIdx.x * 256 + threadIdx.x;   // 0..32767
  int n_c = t & 511;
  int kc  = t >> 9;            // k-chunk of 8: 0..63
  int kt = kc >> 2, c = kc & 3;
  int g = n_c >> 5, j = n_c & 31;
  const float* src = (j < 16) ? W1 : W3;
  int h = g * 16 + (j & 15);
  int kk = kc * 8;
  bf16x8 v;
  #pragma unroll
  for (int r = 0; r < 8; ++r) v[r] = f2bf(src[(kk + r) * H_DIM + h]);
  *(bf16x8*)(wc + kt * 16384 + (c * 512 + n_c) * 8) = v;
}

// ---------------- k1: fused gate GEMM (bf16 MFMA) + logits = gate@W2 ----------------
// 512 thr = 8 waves (2 row x 4 col), wave tile 64x128, block tile 128x512.
// BK=32, 16 K-steps, A+B double-buffered, B via global_load_lds (chunk-major,
// bank-conflict-free), A reg-staged fp32->bf16. Prefetch issued at step start.
__global__ __launch_bounds__(512, 2) void k_gate_logits(
    const float* __restrict__ x,
    const short* __restrict__ wc,
    const float* __restrict__ b1, const float* __restrict__ b3,
    const float* __restrict__ W2,
    float* __restrict__ logits)
{
  __shared__ __align__(16) short as[2][4096];    // A tile: (c*128 + r)*8 + rem   (8 KB each)
  __shared__ __align__(16) short bs[2][16384];   // B tile: (c*512 + col)*8 + rem (32 KB each)
  __shared__ __align__(16) float w2s[H_DIM * 4]; // 4 KB
  __shared__ float lpart[4][128][4];             // 8 KB

  const int tid  = threadIdx.x;
  const int lane = tid & 63;
  const int wid  = tid >> 6;
  const int wm   = wid >> 2;      // 0..1  (64-row band)
  const int wn   = wid & 3;       // 0..3  (128-col band)
  const int l15  = lane & 15;
  const int q    = lane >> 4;     // k-chunk within 32
  const long row0 = (long)blockIdx.x * 128;

  if (tid < 256) ((f32x4*)w2s)[tid] = ((const f32x4*)W2)[tid];

  f32x4 acc[4][8];
  #pragma unroll
  for (int mf = 0; mf < 4; ++mf)
    #pragma unroll
    for (int nf = 0; nf < 8; ++nf) acc[mf][nf] = (f32x4){0.f, 0.f, 0.f, 0.f};

  // A staging: one 8-elem chunk per thread: row ar, k-chunk ac
  const int ar = tid & 127;
  const int ac = tid >> 7;                 // 0..3
  const float* axp = x + (row0 + ar) * D_IN + ac * 8;

  // B staging: per-lane global src (linear copy of the 32 KB tile)
  const short* bg = wc + wid * 2048 + lane * 8;

  float4 a0, a1;
#define ALOAD(s) { const float4* p = (const float4*)(axp + (s) * 32); a0 = p[0]; a1 = p[1]; }
#define ASTORE(buf) { bf16x8 v; \
    v[0]=f2bf(a0.x); v[1]=f2bf(a0.y); v[2]=f2bf(a0.z); v[3]=f2bf(a0.w); \
    v[4]=f2bf(a1.x); v[5]=f2bf(a1.y); v[6]=f2bf(a1.z); v[7]=f2bf(a1.w); \
    *(bf16x8*)&as[buf][(ac * 128 + ar) * 8] = v; }
#define BSTAGE(s, buf) { \
    const short* g_ = bg + (s) * 16384; \
    _Pragma("unroll") \
    for (int i_ = 0; i_ < 4; ++i_) \
      __builtin_amdgcn_global_load_lds( \
        (const __attribute__((address_space(1))) unsigned int*)(g_ + i_ * 512), \
        (__attribute__((address_space(3))) unsigned int*)&bs[buf][wid * 2048 + i_ * 512], \
        16, 0, 0); }

  // prologue: stage tile 0
  ALOAD(0); BSTAGE(0, 0); ASTORE(0);
  __syncthreads();

  for (int s = 0; s < 16; ++s) {
    const int cb = s & 1;
    if (s < 15) { ALOAD(s + 1); BSTAGE(s + 1, cb ^ 1); }   // prefetch at step start
    bf16x8 af[4], bf[8];
    #pragma unroll
    for (int mf = 0; mf < 4; ++mf)
      af[mf] = *(const bf16x8*)&as[cb][(q * 128 + wm * 64 + mf * 16 + l15) * 8];
    #pragma unroll
    for (int nf = 0; nf < 8; ++nf)
      bf[nf] = *(const bf16x8*)&bs[cb][(q * 512 + wn * 128 + nf * 16 + l15) * 8];
    #pragma unroll
    for (int mf = 0; mf < 4; ++mf)
      #pragma unroll
      for (int nf = 0; nf < 8; ++nf)
        acc[mf][nf] = __builtin_amdgcn_mfma_f32_16x16x32_bf16(af[mf], bf[nf], acc[mf][nf], 0, 0, 0);
    if (s < 15) ASTORE(cb ^ 1);
    __syncthreads();
  }

  // epilogue: gate = tanh(h1+b1)*sigmoid(h3+b3); partial logits = gate @ W2
  // frag pair (2p, 2p+1) -> H col h = wn*64 + p*16 + l15
  float b1v[4], b3v[4];
  f32x4 wv[4];
  #pragma unroll
  for (int p = 0; p < 4; ++p) {
    int h = wn * 64 + p * 16 + l15;
    b1v[p] = b1[h];
    b3v[p] = b3[h];
    wv[p] = *(const f32x4*)&w2s[h * 4];
  }
  float pl[4][4][4];
  #pragma unroll
  for (int mf = 0; mf < 4; ++mf)
    #pragma unroll
    for (int j = 0; j < 4; ++j)
      #pragma unroll
      for (int kk = 0; kk < 4; ++kk) pl[mf][j][kk] = 0.f;

  #pragma unroll
  for (int mf = 0; mf < 4; ++mf)
    #pragma unroll
    for (int p = 0; p < 4; ++p)
      #pragma unroll
      for (int j = 0; j < 4; ++j) {
        float h1 = acc[mf][2 * p][j]     + b1v[p];
        float h3 = acc[mf][2 * p + 1][j] + b3v[p];
        float th = 1.f - __fdividef(2.f, __expf(2.f * h1) + 1.f);
        float sg = __fdividef(1.f, 1.f + __expf(-h3));
        float g = th * sg;
        pl[mf][j][0] += g * wv[p][0];
        pl[mf][j][1] += g * wv[p][1];
        pl[mf][j][2] += g * wv[p][2];
        pl[mf][j][3] += g * wv[p][3];
      }

  // reduce over the 16 cols (l15) of each lane-group
  #pragma unroll
  for (int off = 1; off < 16; off <<= 1)
    #pragma unroll
    for (int mf = 0; mf < 4; ++mf)
      #pragma unroll
      for (int j = 0; j < 4; ++j)
        #pragma unroll
        for (int kk = 0; kk < 4; ++kk)
          pl[mf][j][kk] += __shfl_xor(pl[mf][j][kk], off);

  if (l15 == 0) {
    #pragma unroll
    for (int mf = 0; mf < 4; ++mf)
      #pragma unroll
      for (int j = 0; j < 4; ++j)
        #pragma unroll
        for (int kk = 0; kk < 4; ++kk)
          lpart[wn][wm * 64 + mf * 16 + q * 4 + j][kk] = pl[mf][j][kk];
  }
  __syncthreads();

  {
    int r = tid >> 2, kk = tid & 3;   // 512 threads = 128 rows x 4 heads
    logits[(row0 + r) * 4 + kk] =
        lpart[0][r][kk] + lpart[1][r][kk] + lpart[2][r][kk] + lpart[3][r][kk];
  }
}

// ---------------- k2: per-(bag, head) softmax max & sum ----------------
__global__ __launch_bounds__(256) void k_softmax_stats(const float* __restrict__ logits,
                                                       float* __restrict__ mx,
                                                       float* __restrict__ sm) {
  const int b = blockIdx.x, tid = threadIdx.x;
  const int lane = tid & 63, wid = tid >> 6;
  const float4* L = (const float4*)logits + (long)b * L_BAG;

  float m0 = -3e38f, m1 = m0, m2 = m0, m3 = m0;
  #pragma unroll
  for (int i = 0; i < 8; ++i) {
    float4 v = L[i * 256 + tid];
    m0 = fmaxf(m0, v.x); m1 = fmaxf(m1, v.y); m2 = fmaxf(m2, v.z); m3 = fmaxf(m3, v.w);
  }
  #pragma unroll
  for (int o = 1; o < 64; o <<= 1) {
    m0 = fmaxf(m0, __shfl_xor(m0, o)); m1 = fmaxf(m1, __shfl_xor(m1, o));
    m2 = fmaxf(m2, __shfl_xor(m2, o)); m3 = fmaxf(m3, __shfl_xor(m3, o));
  }
  __shared__ float wr[4][4];
  __shared__ float bm[4];
  if (lane == 0) { wr[wid][0] = m0; wr[wid][1] = m1; wr[wid][2] = m2; wr[wid][3] = m3; }
  __syncthreads();
  if (tid < 4) bm[tid] = fmaxf(fmaxf(wr[0][tid], wr[1][tid]), fmaxf(wr[2][tid], wr[3][tid]));
  __syncthreads();
  m0 = bm[0]; m1 = bm[1]; m2 = bm[2]; m3 = bm[3];

  float s0 = 0.f, s1 = 0.f, s2 = 0.f, s3 = 0.f;
  #pragma unroll
  for (int i = 0; i < 8; ++i) {
    float4 v = L[i * 256 + tid];
    s0 += __expf(v.x - m0); s1 += __expf(v.y - m1);
    s2 += __expf(v.z - m2); s3 += __expf(v.w - m3);
  }
  #pragma unroll
  for (int o = 1; o < 64; o <<= 1) {
    s0 += __shfl_xor(s0, o); s1 += __shfl_xor(s1, o);
    s2 += __shfl_xor(s2, o); s3 += __shfl_xor(s3, o);
  }
  __syncthreads();
  if (lane == 0) { wr[wid][0] = s0; wr[wid][1] = s1; wr[wid][2] = s2; wr[wid][3] = s3; }
  __syncthreads();
  if (tid < 4) {
    mx[b * 4 + tid] = bm[tid];
    sm[b * 4 + tid] = wr[0][tid] + wr[1][tid] + wr[2][tid] + wr[3][tid];
  }
}

// ---------------- k3: partial weighted sums over 128-row chunks ----------------
__global__ __launch_bounds__(128) void k_weighted_partial(const float* __restrict__ x,
                                                          const float* __restrict__ logits,
                                                          const float* __restrict__ mx,
                                                          float* __restrict__ part) {
  const int chunk = blockIdx.x;   // 0..15
  const int b = blockIdx.y;       // 0..31
  const int tid = threadIdx.x;    // 0..127
  const long l0 = (long)b * L_BAG + chunk * 128;

  __shared__ float ep[128][4];
  {
    float4 lg = ((const float4*)logits)[l0 + tid];
    ep[tid][0] = __expf(lg.x - mx[b * 4 + 0]);
    ep[tid][1] = __expf(lg.y - mx[b * 4 + 1]);
    ep[tid][2] = __expf(lg.z - mx[b * 4 + 2]);
    ep[tid][3] = __expf(lg.w - mx[b * 4 + 3]);
  }
  __syncthreads();

  float4 a0 = {0,0,0,0}, a1 = {0,0,0,0}, a2 = {0,0,0,0}, a3 = {0,0,0,0};
  const float4* xp = (const float4*)(x + l0 * D_IN) + tid;
  #pragma unroll 4
  for (int l = 0; l < 128; ++l) {
    float4 xv = xp[l * 128];
    float e0 = ep[l][0], e1 = ep[l][1], e2 = ep[l][2], e3 = ep[l][3];
    a0.x += e0 * xv.x; a0.y += e0 * xv.y; a0.z += e0 * xv.z; a0.w += e0 * xv.w;
    a1.x += e1 * xv.x; a1.y += e1 * xv.y; a1.z += e1 * xv.z; a1.w += e1 * xv.w;
    a2.x += e2 * xv.x; a2.y += e2 * xv.y; a2.z += e2 * xv.z; a2.w += e2 * xv.w;
    a3.x += e3 * xv.x; a3.y += e3 * xv.y; a3.z += e3 * xv.z; a3.w += e3 * xv.w;
  }
  long base = ((long)chunk * 32 + b) * 2048 + tid * 4;
  *(float4*)&part[base +    0] = a0;
  *(float4*)&part[base +  512] = a1;
  *(float4*)&part[base + 1024] = a2;
  *(float4*)&part[base + 1536] = a3;
}

// ---------------- k4: reduce chunks, divide by softmax sum ----------------
__global__ __launch_bounds__(256) void k_finalize(const float* __restrict__ part,
                                                  const float* __restrict__ sm,
                                                  float* __restrict__ out) {
  int idx = blockIdx.x * 256 + threadIdx.x;  // 0..65535 = b*2048 + k*512 + d
  int b = idx >> 11, k = (idx >> 9) & 3;
  float s = 0.f;
  #pragma unroll
  for (int c = 0; c < 16; ++c) s += part[c * 65536 + idx];
  out[idx] = s / sm[b * 4 + k];
}

extern "C" void kernel_launch(void* const* d_in, const int* in_sizes, int n_in,
                              void* d_out, int out_size, void* d_ws, size_t ws_size,
                              hipStream_t stream) {
  const float* x  = (const float*)d_in[0];
  const float* W1 = (const float*)d_in[1];
  const float* b1 = (const float*)d_in[2];
  const float* W3 = (const float*)d_in[3];
  const float* b3 = (const float*)d_in[4];
  const float* W2 = (const float*)d_in[5];
  // d_in[6] = b2: constant over softmax axis -> cancels; d_in[7] = bag_lengths: shapes only
  float* out = (float*)d_out;

  char* ws = (char*)d_ws;                       // ~5.6 MB used
  short* wc     = (short*)(ws + 0);             // 512 KB (concat bf16 weights)
  float* logits = (float*)(ws + 524288);        // 1 MB
  float* mx     = (float*)(ws + 1572864);       // 512 B
  float* sm     = (float*)(ws + 1573376);       // 512 B
  float* part   = (float*)(ws + 1573888);       // 4 MB

  hipLaunchKernelGGL(k_prep_w,          dim3(128),     dim3(256), 0, stream, W1, W3, wc);
  hipLaunchKernelGGL(k_gate_logits,     dim3(512),     dim3(512), 0, stream, x, wc, b1, b3, W2, logits);
  hipLaunchKernelGGL(k_softmax_stats,   dim3(32),      dim3(256), 0, stream, logits, mx, sm);
  hipLaunchKernelGGL(k_weighted_partial,dim3(16, 32),  dim3(128), 0, stream, x, logits, mx, part);
  hipLaunchKernelGGL(k_finalize,        dim3(256),     dim3(256), 0, stream, part, sm, out);
}